// Round 7
// baseline (953.014 us; speedup 1.0000x reference)
//
#include <hip/hip_runtime.h>
#include <math.h>
#include <float.h>

#define BB 32
#define CC 64
#define KK 8192
#define NPIX 256
#define NELEM (BB*CC*NPIX)  // 524288

// init zr/out + wsq in one launch
__global__ void k_prep(const float* __restrict__ f, float* __restrict__ zr,
                       float* __restrict__ out, const float* __restrict__ emb,
                       float* __restrict__ wsq32) {
  int i = blockIdx.x * 256 + threadIdx.x;
  if (i < NELEM) { zr[i] = f[i]; out[i] = 0.f; }
  if (i < KK) {
    const float* row = emb + i * 64;
    double s = 0.0;
    #pragma unroll
    for (int c = 0; c < 64; ++c) s += (double)row[c] * (double)row[c];
    wsq32[i] = (float)s;   // within ~1 ulp of np pairwise-f32: argmin-safe
  }
}

// numpy-exact area mean: pairwise row sum (n=16: fold8+tree; n=8: tree; n<8 seq),
// sequential dy accumulation, * exact pow2 scale.
__global__ void k_down(const float* __restrict__ zr, float* __restrict__ zd, int pn) {
#pragma clang fp contract(off)
  int i = blockIdx.x * 256 + threadIdx.x;
  int pnpn = pn * pn;
  int n = BB * CC * pnpn;
  if (i >= n) return;
  int x = i % pn; int y = (i / pn) % pn; int bc = i / pnpn;
  int bs = 16 / pn;
  const float* src = zr + bc * NPIX + (y * bs) * 16 + x * bs;
  float acc = 0.f;
  for (int dy = 0; dy < bs; ++dy) {
    const float* a = src + dy * 16;
    float s;
    if (bs == 16) {
      float r[8];
      #pragma unroll
      for (int j = 0; j < 8; ++j) r[j] = a[j] + a[8 + j];
      s = ((r[0] + r[1]) + (r[2] + r[3])) + ((r[4] + r[5]) + (r[6] + r[7]));
    } else if (bs == 8) {
      s = ((a[0] + a[1]) + (a[2] + a[3])) + ((a[4] + a[5]) + (a[6] + a[7]));
    } else if (bs == 4) {
      s = ((a[0] + a[1]) + a[2]) + a[3];
    } else {
      s = a[0] + a[1];
    }
    acc = acc + s;
  }
  zd[i] = acc * (1.f / (bs * bs));
}

// ---- argmin, small scales (32 vectors per block share LDS z-tile) ----
__global__ __launch_bounds__(256, 4) void k_argmin(
    const float* __restrict__ zd, const float* __restrict__ emb,
    const float* __restrict__ wsq32,
    float* __restrict__ pd, int* __restrict__ pi,
    int numVec, int pnpn, int kchunk) {
#pragma clang fp contract(off)
  __shared__ __align__(16) float zt[32][68];
  __shared__ __align__(16) float et[64 * 64];
  __shared__ float ws_s[64];
  __shared__ float red_d[256];
  __shared__ int   red_i[256];
  int tid = threadIdx.x;
  int v0 = blockIdx.x * 32;
  int kbase = blockIdx.y * kchunk;

  for (int idx = tid; idx < 32 * 64; idx += 256) {
    int v = idx >> 6, c = idx & 63;
    int vi = v0 + v;
    float val = 0.f;
    if (vi < numVec) {
      int b = vi / pnpn, p = vi % pnpn;
      val = zd[(b * 64 + c) * pnpn + p];
    }
    zt[v][c] = val;
  }
  __syncthreads();

  const int v = tid & 31, kg = tid >> 5;
  float4 z4[16];
  #pragma unroll
  for (int i = 0; i < 16; ++i) z4[i] = *reinterpret_cast<float4*>(&zt[v][i * 4]);
  float zsq = 0.f;   // scheme-free: uniform ulp shift preserves argmin
  #pragma unroll
  for (int i = 0; i < 16; ++i)
    zsq += z4[i].x * z4[i].x + z4[i].y * z4[i].y + z4[i].z * z4[i].z + z4[i].w * z4[i].w;

  float bd = FLT_MAX; int bi = 0x7fffffff;
  for (int k0 = 0; k0 < kchunk; k0 += 64) {
    __syncthreads();
    {
      const float4* gsrc = reinterpret_cast<const float4*>(emb + (size_t)(kbase + k0) * 64);
      float4* ldst = reinterpret_cast<float4*>(et);
      #pragma unroll
      for (int idx = 0; idx < 4; ++idx)
        ldst[tid + idx * 256] = gsrc[tid + idx * 256];
    }
    if (tid < 64) ws_s[tid] = wsq32[kbase + k0 + tid];
    __syncthreads();
    #pragma unroll
    for (int j = 0; j < 8; ++j) {
      int kl = kg * 8 + j;
      const float4* e4 = reinterpret_cast<const float4*>(&et[kl * 64]);
      float acc = 0.f;
      #pragma unroll
      for (int i = 0; i < 16; ++i) {
        float4 e = e4[i];
        acc = __builtin_fmaf(z4[i].x, e.x, acc);
        acc = __builtin_fmaf(z4[i].y, e.y, acc);
        acc = __builtin_fmaf(z4[i].z, e.z, acc);
        acc = __builtin_fmaf(z4[i].w, e.w, acc);
      }
      float t1 = zsq + ws_s[kl];
      float d  = t1 - 2.0f * acc;
      if (d < bd) { bd = d; bi = kbase + k0 + kl; }   // strict <: first index
    }
  }
  red_d[tid] = bd; red_i[tid] = bi;
  __syncthreads();
  if (tid < 32) {
    float fb = red_d[tid]; int fi = red_i[tid];
    #pragma unroll
    for (int g = 1; g < 8; ++g) {
      float cd = red_d[g * 32 + tid]; int ci = red_i[g * 32 + tid];
      if (cd < fb || (cd == fb && ci < fi)) { fb = cd; fi = ci; }
    }
    int vi = v0 + tid;
    if (vi < numVec) {
      pd[blockIdx.y * numVec + vi] = fb;
      pi[blockIdx.y * numVec + vi] = fi;
    }
  }
}

// ---- argmin, big scales: register-tiled GEMM, prefetched & reg-transposed.
// Block = 64 vecs x 64 codes, 256 thr as 16x16, 4x4 acc/thread.
// grid (numVec/64, ksplit).
__global__ __launch_bounds__(256, 4) void k_argmin_mm(
    const float* __restrict__ zd, const float* __restrict__ emb,
    const float* __restrict__ wsq32,
    float* __restrict__ pd, int* __restrict__ pi,
    int numVec, int pnpn, int kchunk) {
#pragma clang fp contract(off)
  __shared__ __align__(16) float zs[64 * 64];   // [c][v], unpadded (reads broadcast)
  __shared__ __align__(16) float es[64 * 68];   // [c][k], padded for write spread
  __shared__ float ws_s[64];
  __shared__ float zsq_s[64];
  int tid = threadIdx.x;
  int tx = tid & 15, ty = tid >> 4;
  int tx4 = tx * 4, ty4 = ty * 4;
  int vi0 = blockIdx.x * 64;
  int kbase = blockIdx.y * kchunk;
  int b = vi0 / pnpn, p0 = vi0 % pnpn;
  const float* zbase = zd + (size_t)b * 64 * pnpn + p0;

  #pragma unroll
  for (int r = 0; r < 16; ++r) {               // z-tile, coalesced, stride-1 writes
    int idx = r * 256 + tid;
    int c = idx >> 6, vv = idx & 63;
    zs[c * 64 + vv] = zbase[(size_t)c * pnpn + vv];
  }
  __syncthreads();
  if (tid < 64) {
    // same association as proven kernel: s += ((x*x + y*y) + z*z) + w*w
    float s = 0.f;
    #pragma unroll
    for (int i = 0; i < 16; ++i) {
      float x = zs[(4 * i + 0) * 64 + tid], y = zs[(4 * i + 1) * 64 + tid];
      float z = zs[(4 * i + 2) * 64 + tid], w = zs[(4 * i + 3) * 64 + tid];
      s += x * x + y * y + z * z + w * w;
    }
    zsq_s[tid] = s;
  }

  float bd[4] = {FLT_MAX, FLT_MAX, FLT_MAX, FLT_MAX};
  int   bi[4] = {0x7fffffff, 0x7fffffff, 0x7fffffff, 0x7fffffff};

  // thread's staging sub-block: 4 consecutive k rows (q*4..), 4 consecutive c (cq*4..)
  const int q = tid >> 4, cq = tid & 15;
  float4 ereg[4];
  {
    const float4* g0 = reinterpret_cast<const float4*>(emb + (size_t)kbase * 64);
    #pragma unroll
    for (int r = 0; r < 4; ++r) ereg[r] = g0[(q * 4 + r) * 16 + cq];
  }
  float wreg = (tid < 64) ? wsq32[kbase + tid] : 0.f;

  int ntile = kchunk >> 6;
  for (int kt = 0; kt < ntile; ++kt) {
    __syncthreads();                 // es free; (kt==0) zs/zsq ready
    {
      // 4x4 register transpose -> b128 writes along k (4-way spread)
      int k0 = q * 4;
      float4 w4;
      w4.x = ereg[0].x; w4.y = ereg[1].x; w4.z = ereg[2].x; w4.w = ereg[3].x;
      *reinterpret_cast<float4*>(&es[(cq * 4 + 0) * 68 + k0]) = w4;
      w4.x = ereg[0].y; w4.y = ereg[1].y; w4.z = ereg[2].y; w4.w = ereg[3].y;
      *reinterpret_cast<float4*>(&es[(cq * 4 + 1) * 68 + k0]) = w4;
      w4.x = ereg[0].z; w4.y = ereg[1].z; w4.z = ereg[2].z; w4.w = ereg[3].z;
      *reinterpret_cast<float4*>(&es[(cq * 4 + 2) * 68 + k0]) = w4;
      w4.x = ereg[0].w; w4.y = ereg[1].w; w4.z = ereg[2].w; w4.w = ereg[3].w;
      *reinterpret_cast<float4*>(&es[(cq * 4 + 3) * 68 + k0]) = w4;
    }
    if (tid < 64) ws_s[tid] = wreg;
    __syncthreads();
    if (kt + 1 < ntile) {            // prefetch next tile; latency hides under FMAs
      const float4* g2 = reinterpret_cast<const float4*>(emb + (size_t)(kbase + (kt + 1) * 64) * 64);
      #pragma unroll
      for (int r = 0; r < 4; ++r) ereg[r] = g2[(q * 4 + r) * 16 + cq];
      if (tid < 64) wreg = wsq32[kbase + (kt + 1) * 64 + tid];
    }

    float acc[4][4] = {};
    #pragma unroll 8
    for (int c = 0; c < 64; ++c) {
      float4 zf = *reinterpret_cast<const float4*>(&zs[c * 64 + ty4]);
      float4 ef = *reinterpret_cast<const float4*>(&es[c * 68 + tx4]);
      float z_[4] = {zf.x, zf.y, zf.z, zf.w};
      float e_[4] = {ef.x, ef.y, ef.z, ef.w};
      #pragma unroll
      for (int i = 0; i < 4; ++i)
        #pragma unroll
        for (int j = 0; j < 4; ++j)
          acc[i][j] = __builtin_fmaf(z_[i], e_[j], acc[i][j]);
    }

    #pragma unroll
    for (int i = 0; i < 4; ++i) {
      float zq = zsq_s[ty4 + i];
      #pragma unroll
      for (int j = 0; j < 4; ++j) {
        float t1 = zq + ws_s[tx4 + j];
        float d  = t1 - 2.0f * acc[i][j];
        int ki = kbase + kt * 64 + tx4 + j;
        if (d < bd[i] || (d == bd[i] && ki < bi[i])) { bd[i] = d; bi[i] = ki; }
      }
    }
  }

  // reduce across tx (16 lanes, xor masks 1..8 stay within the tx group)
  #pragma unroll
  for (int i = 0; i < 4; ++i) {
    float d = bd[i]; int ix = bi[i];
    #pragma unroll
    for (int m = 1; m < 16; m <<= 1) {
      float od = __shfl_xor(d, m, 64);
      int   oi = __shfl_xor(ix, m, 64);
      if (od < d || (od == d && oi < ix)) { d = od; ix = oi; }
    }
    if (tx == 0) {
      pd[blockIdx.y * numVec + vi0 + ty4 + i] = d;
      pi[blockIdx.y * numVec + vi0 + ty4 + i] = ix;
    }
  }
}

// ---- fused ksplit-reduce + cubic upsample (or direct gather for pn==16) ----
// grid NELEM/256. Block = fixed (b, c), covers all 256 output pixels.
__global__ __launch_bounds__(256) void k_up(
    const float* __restrict__ pd, const int* __restrict__ pi,
    const float* __restrict__ emb, float* __restrict__ hup,
    int pn, int ksplit) {
  __shared__ float td[256];
  __shared__ int   ti[256];
  __shared__ int   tok_s[256];
  __shared__ float wsh[16][4];
  __shared__ int   i0sh[16];

  int t = threadIdx.x;
  int i = blockIdx.x * 256 + t;
  int p = i & 255; int c = (i >> 8) & 63; int b = i >> 14;
  int P = pn * pn;
  int numVec = BB * P;
  int R = 256 / P;          // split-groups
  int v = t % P, sg = t / P;

  float bd = FLT_MAX; int bi = 0x7fffffff;
  for (int s = sg; s < ksplit; s += R) {
    float cd = pd[s * numVec + b * P + v]; int ci = pi[s * numVec + b * P + v];
    if (cd < bd || (cd == bd && ci < bi)) { bd = cd; bi = ci; }
  }
  td[t] = bd; ti[t] = bi;
  __syncthreads();
  for (int r = R >> 1; r >= 1; r >>= 1) {
    if (sg < r) {
      float cd = td[t + r * P]; int ci = ti[t + r * P];
      if (cd < td[t] || (cd == td[t] && ci < ti[t])) { td[t] = cd; ti[t] = ci; }
    }
    __syncthreads();
  }
  if (t < P) tok_s[t] = ti[t];
  if (pn < 16 && t < 16) {
    // cubic (Keys a=-0.5) weights, f64, bit-identical to jax's (normalized window)
    double s = (t + 0.5) * ((double)pn / 16.0) - 0.5;
    int i0 = (int)floor(s) - 1;
    int hi = pn - 4; if (hi < 0) hi = 0;
    if (i0 < 0) i0 = 0; if (i0 > hi) i0 = hi;
    double wv[4]; double sum = 0.0;
    #pragma unroll
    for (int qq = 0; qq < 4; ++qq) {
      int ii = i0 + qq;
      double w = 0.0;
      if (ii < pn) {
        double xx = fabs(s - (double)ii);
        if (xx < 1.0)       w = ((1.5 * xx - 2.5) * xx) * xx + 1.0;
        else if (xx < 2.0)  w = ((-0.5 * xx + 2.5) * xx - 4.0) * xx + 2.0;
      }
      wv[qq] = w; sum += w;
    }
    i0sh[t] = i0;
    #pragma unroll
    for (int qq = 0; qq < 4; ++qq) wsh[t][qq] = (float)(wv[qq] / sum);
  }
  __syncthreads();

  if (pn == 16) { hup[i] = emb[(size_t)tok_s[p] * 64 + c]; return; }

  int y = p >> 4, x = p & 15;
  int iy0 = i0sh[y], ix0 = i0sh[x];
  float acc = 0.f;
  #pragma unroll
  for (int ty = 0; ty < 4; ++ty) {
    float wy = wsh[y][ty];
    int iy = iy0 + ty; if (iy > pn - 1) iy = pn - 1;  // zero-weight taps: clamp keeps reads in-bounds
    float tmp = 0.f;
    #pragma unroll
    for (int tx = 0; tx < 4; ++tx) {
      float wx = wsh[x][tx];
      int ix = ix0 + tx; if (ix > pn - 1) ix = pn - 1;
      tmp += wx * emb[(size_t)tok_s[iy * pn + ix] * 64 + c];
    }
    acc += wy * tmp;
  }
  hup[i] = acc;
}

// grid = (B, 16): one batch image x 4 output channels. ic streamed in 16-chunks.
// Weights read via wave-uniform global pointers -> scalar loads, no LDS.
__global__ __launch_bounds__(256) void k_conv(
    const float* __restrict__ hup, const float* __restrict__ w,
    const float* __restrict__ bias, float* __restrict__ out, float* __restrict__ zr) {
  __shared__ __align__(16) float ins[16][NPIX];
  int tid = threadIdx.x;
  int b = blockIdx.x;
  int ocg = blockIdx.y;
  const int y = tid >> 4, x = tid & 15;

  float acc[4];
  #pragma unroll
  for (int j = 0; j < 4; ++j) acc[j] = bias[ocg * 4 + j];

  const float4* hup4 = reinterpret_cast<const float4*>(hup + (size_t)b * 64 * NPIX);
  float4 sreg[4];
  #pragma unroll
  for (int r = 0; r < 4; ++r) sreg[r] = hup4[r * 256 + tid];   // chunk 0

  for (int cc = 0; cc < 4; ++cc) {
    __syncthreads();
    #pragma unroll
    for (int r = 0; r < 4; ++r)
      reinterpret_cast<float4*>(ins)[r * 256 + tid] = sreg[r];
    __syncthreads();
    if (cc < 3) {
      #pragma unroll
      for (int r = 0; r < 4; ++r) sreg[r] = hup4[(cc + 1) * 1024 + r * 256 + tid];
    }
    #pragma unroll
    for (int icl = 0; icl < 16; ++icl) {
      float vtap[9];
      #pragma unroll
      for (int dy = 0; dy < 3; ++dy)
        #pragma unroll
        for (int dx = 0; dx < 3; ++dx) {
          int yy = y + dy - 1, xx = x + dx - 1;
          vtap[dy * 3 + dx] = (yy >= 0 && yy < 16 && xx >= 0 && xx < 16)
                              ? ins[icl][yy * 16 + xx] : 0.f;
        }
      int ic = cc * 16 + icl;
      #pragma unroll
      for (int j = 0; j < 4; ++j) {
        const float* wp = w + ((size_t)(ocg * 4 + j) * 64 + ic) * 9;  // uniform -> s_load
        float a = acc[j];
        #pragma unroll
        for (int t = 0; t < 9; ++t) a += vtap[t] * wp[t];
        acc[j] = a;
      }
    }
  }

  #pragma unroll
  for (int j = 0; j < 4; ++j) {
    int oc = ocg * 4 + j;
    size_t gi = ((size_t)b * 64 + oc) * NPIX + tid;
    float h = hup[gi];
    float ho = 0.5f * h + 0.5f * acc[j];
    out[gi] += ho;
    zr[gi]  -= ho;
  }
}

extern "C" void kernel_launch(void* const* d_in, const int* in_sizes, int n_in,
                              void* d_out, int out_size, void* d_ws, size_t ws_size,
                              hipStream_t stream) {
  const float* f    = (const float*)d_in[0];
  const float* emb  = (const float*)d_in[1];
  const float* phiw = (const float*)d_in[2];
  const float* phib = (const float*)d_in[3];
  float* out = (float*)d_out;

  float* ws  = (float*)d_ws;
  float* zr    = ws;                       // 524288
  float* zd    = ws + 524288;              // 524288
  float* hup   = ws + 1048576;             // 524288
  float* wsq32 = ws + 1572864;             // 8192
  float* pd    = ws + 1581056;             // 65536 (max ksplit*numVec)
  int*   pi    = (int*)(ws + 1646592);     // 65536

  // --- PHI_IDX: replicate numpy linspace + argmin in doubles ---
  double start = 1.0 / 3.0 / 4.0;
  double stop  = 1.0 - 1.0 / 3.0 / 4.0;
  double step  = (stop - start) / 3.0;
  double ticks[4] = { start, 1.0 * step + start, 2.0 * step + start, stop };
  int phi_idx[5];
  for (int si = 0; si < 5; ++si) {
    double xx = si / 4.0;
    int bj = 0; double bdd = fabs(ticks[0] - xx);
    for (int j = 1; j < 4; ++j) { double dd = fabs(ticks[j] - xx); if (dd < bdd) { bdd = dd; bj = j; } }
    phi_idx[si] = bj;
  }

  static const int MSarr[5] = {1, 2, 4, 8, 16};

  k_prep<<<NELEM / 256, 256, 0, stream>>>(f, zr, out, emb, wsq32);

  const int KS[5] = {128, 32, 16, 32, 8};
  for (int si = 0; si < 5; ++si) {
    int pn = MSarr[si], pnpn = pn * pn, numVec = BB * pnpn;
    const float* zsrc;
    if (si < 4) {
      int n = BB * CC * pnpn;
      k_down<<<(n + 255) / 256, 256, 0, stream>>>(zr, zd, pn);
      zsrc = zd;
    } else {
      zsrc = zr;
    }
    int ksplit = KS[si], kchunk = KK / ksplit;
    if (si >= 3) {
      dim3 g(numVec / 64, ksplit);
      k_argmin_mm<<<g, 256, 0, stream>>>(zsrc, emb, wsq32, pd, pi, numVec, pnpn, kchunk);
    } else {
      dim3 g((numVec + 31) / 32, ksplit);
      k_argmin<<<g, 256, 0, stream>>>(zsrc, emb, wsq32, pd, pi, numVec, pnpn, kchunk);
    }
    k_up<<<NELEM / 256, 256, 0, stream>>>(pd, pi, emb, hup, pn, ksplit);
    int pidx = phi_idx[si];
    k_conv<<<dim3(BB, 16), 256, 0, stream>>>(hup, phiw + pidx * 64 * 64 * 9,
                                             phib + pidx * 64, out, zr);
  }
}

// Round 8
// 423.985 us; speedup vs baseline: 2.2478x; 2.2478x over previous
//
#include <hip/hip_runtime.h>
#include <math.h>
#include <float.h>

#define BB 32
#define CC 64
#define KK 8192
#define NPIX 256
#define NELEM (BB*CC*NPIX)  // 524288

// init zr/out + wsq in one launch
__global__ void k_prep(const float* __restrict__ f, float* __restrict__ zr,
                       float* __restrict__ out, const float* __restrict__ emb,
                       float* __restrict__ wsq32) {
  int i = blockIdx.x * 256 + threadIdx.x;
  if (i < NELEM) { zr[i] = f[i]; out[i] = 0.f; }
  if (i < KK) {
    const float* row = emb + i * 64;
    double s = 0.0;
    #pragma unroll
    for (int c = 0; c < 64; ++c) s += (double)row[c] * (double)row[c];
    wsq32[i] = (float)s;   // within ~1 ulp of np pairwise-f32: argmin-safe
  }
}

// numpy-exact area mean: pairwise row sum (n=16: fold8+tree; n=8: tree; n<8 seq),
// sequential dy accumulation, * exact pow2 scale.
__global__ void k_down(const float* __restrict__ zr, float* __restrict__ zd, int pn) {
#pragma clang fp contract(off)
  int i = blockIdx.x * 256 + threadIdx.x;
  int pnpn = pn * pn;
  int n = BB * CC * pnpn;
  if (i >= n) return;
  int x = i % pn; int y = (i / pn) % pn; int bc = i / pnpn;
  int bs = 16 / pn;
  const float* src = zr + bc * NPIX + (y * bs) * 16 + x * bs;
  float acc = 0.f;
  for (int dy = 0; dy < bs; ++dy) {
    const float* a = src + dy * 16;
    float s;
    if (bs == 16) {
      float r[8];
      #pragma unroll
      for (int j = 0; j < 8; ++j) r[j] = a[j] + a[8 + j];
      s = ((r[0] + r[1]) + (r[2] + r[3])) + ((r[4] + r[5]) + (r[6] + r[7]));
    } else if (bs == 8) {
      s = ((a[0] + a[1]) + (a[2] + a[3])) + ((a[4] + a[5]) + (a[6] + a[7]));
    } else if (bs == 4) {
      s = ((a[0] + a[1]) + a[2]) + a[3];
    } else {
      s = a[0] + a[1];
    }
    acc = acc + s;
  }
  zd[i] = acc * (1.f / (bs * bs));
}

// ---- argmin, small scales (32 vectors per block share LDS z-tile) ----
__global__ __launch_bounds__(256, 4) void k_argmin(
    const float* __restrict__ zd, const float* __restrict__ emb,
    const float* __restrict__ wsq32,
    float* __restrict__ pd, int* __restrict__ pi,
    int numVec, int pnpn, int kchunk) {
#pragma clang fp contract(off)
  __shared__ __align__(16) float zt[32][68];
  __shared__ __align__(16) float et[64 * 64];
  __shared__ float ws_s[64];
  __shared__ float red_d[256];
  __shared__ int   red_i[256];
  int tid = threadIdx.x;
  int v0 = blockIdx.x * 32;
  int kbase = blockIdx.y * kchunk;

  for (int idx = tid; idx < 32 * 64; idx += 256) {
    int v = idx >> 6, c = idx & 63;
    int vi = v0 + v;
    float val = 0.f;
    if (vi < numVec) {
      int b = vi / pnpn, p = vi % pnpn;
      val = zd[(b * 64 + c) * pnpn + p];
    }
    zt[v][c] = val;
  }
  __syncthreads();

  const int v = tid & 31, kg = tid >> 5;
  float4 z4[16];
  #pragma unroll
  for (int i = 0; i < 16; ++i) z4[i] = *reinterpret_cast<float4*>(&zt[v][i * 4]);
  float zsq = 0.f;   // scheme-free: uniform ulp shift preserves argmin
  #pragma unroll
  for (int i = 0; i < 16; ++i)
    zsq += z4[i].x * z4[i].x + z4[i].y * z4[i].y + z4[i].z * z4[i].z + z4[i].w * z4[i].w;

  float bd = FLT_MAX; int bi = 0x7fffffff;
  for (int k0 = 0; k0 < kchunk; k0 += 64) {
    __syncthreads();
    {
      const float4* gsrc = reinterpret_cast<const float4*>(emb + (size_t)(kbase + k0) * 64);
      float4* ldst = reinterpret_cast<float4*>(et);
      #pragma unroll
      for (int idx = 0; idx < 4; ++idx)
        ldst[tid + idx * 256] = gsrc[tid + idx * 256];
    }
    if (tid < 64) ws_s[tid] = wsq32[kbase + k0 + tid];
    __syncthreads();
    #pragma unroll
    for (int j = 0; j < 8; ++j) {
      int kl = kg * 8 + j;
      const float4* e4 = reinterpret_cast<const float4*>(&et[kl * 64]);
      float acc = 0.f;
      #pragma unroll
      for (int i = 0; i < 16; ++i) {
        float4 e = e4[i];
        acc = __builtin_fmaf(z4[i].x, e.x, acc);
        acc = __builtin_fmaf(z4[i].y, e.y, acc);
        acc = __builtin_fmaf(z4[i].z, e.z, acc);
        acc = __builtin_fmaf(z4[i].w, e.w, acc);
      }
      float t1 = zsq + ws_s[kl];
      float d  = t1 - 2.0f * acc;
      if (d < bd) { bd = d; bi = kbase + k0 + kl; }   // strict <: first index
    }
  }
  red_d[tid] = bd; red_i[tid] = bi;
  __syncthreads();
  if (tid < 32) {
    float fb = red_d[tid]; int fi = red_i[tid];
    #pragma unroll
    for (int g = 1; g < 8; ++g) {
      float cd = red_d[g * 32 + tid]; int ci = red_i[g * 32 + tid];
      if (cd < fb || (cd == fb && ci < fi)) { fb = cd; fi = ci; }
    }
    int vi = v0 + tid;
    if (vi < numVec) {
      pd[blockIdx.y * numVec + vi] = fb;
      pi[blockIdx.y * numVec + vi] = fi;
    }
  }
}

// ---- argmin, big scales: register-tiled GEMM, prefetched & reg-transposed.
// Block = 64 vecs x 64 codes, 256 thr as 16x16, 4x4 acc/thread.
// grid (numVec/64, ksplit).
__global__ __launch_bounds__(256, 4) void k_argmin_mm(
    const float* __restrict__ zd, const float* __restrict__ emb,
    const float* __restrict__ wsq32,
    float* __restrict__ pd, int* __restrict__ pi,
    int numVec, int pnpn, int kchunk) {
#pragma clang fp contract(off)
  __shared__ __align__(16) float zs[64 * 64];   // [c][v], unpadded (reads broadcast)
  __shared__ __align__(16) float es[64 * 68];   // [c][k], padded for write spread
  __shared__ float ws_s[64];
  __shared__ float zsq_s[64];
  int tid = threadIdx.x;
  int tx = tid & 15, ty = tid >> 4;
  int tx4 = tx * 4, ty4 = ty * 4;
  int vi0 = blockIdx.x * 64;
  int kbase = blockIdx.y * kchunk;
  int b = vi0 / pnpn, p0 = vi0 % pnpn;
  const float* zbase = zd + (size_t)b * 64 * pnpn + p0;

  #pragma unroll
  for (int r = 0; r < 16; ++r) {               // z-tile, coalesced, stride-1 writes
    int idx = r * 256 + tid;
    int c = idx >> 6, vv = idx & 63;
    zs[c * 64 + vv] = zbase[(size_t)c * pnpn + vv];
  }
  __syncthreads();
  if (tid < 64) {
    // same association as proven kernel: s += ((x*x + y*y) + z*z) + w*w
    float s = 0.f;
    #pragma unroll
    for (int i = 0; i < 16; ++i) {
      float x = zs[(4 * i + 0) * 64 + tid], y = zs[(4 * i + 1) * 64 + tid];
      float z = zs[(4 * i + 2) * 64 + tid], w = zs[(4 * i + 3) * 64 + tid];
      s += x * x + y * y + z * z + w * w;
    }
    zsq_s[tid] = s;
  }

  float bd[4] = {FLT_MAX, FLT_MAX, FLT_MAX, FLT_MAX};
  int   bi[4] = {0x7fffffff, 0x7fffffff, 0x7fffffff, 0x7fffffff};

  // thread's staging sub-block: 4 consecutive k rows (q*4..), 4 consecutive c (cq*4..)
  const int q = tid >> 4, cq = tid & 15;
  float4 ereg[4];
  {
    const float4* g0 = reinterpret_cast<const float4*>(emb + (size_t)kbase * 64);
    #pragma unroll
    for (int r = 0; r < 4; ++r) ereg[r] = g0[(q * 4 + r) * 16 + cq];
  }
  float wreg = (tid < 64) ? wsq32[kbase + tid] : 0.f;

  int ntile = kchunk >> 6;
  for (int kt = 0; kt < ntile; ++kt) {
    __syncthreads();                 // es free; (kt==0) zs/zsq ready
    {
      // 4x4 register transpose -> b128 writes along k (4-way spread)
      int k0 = q * 4;
      float4 w4;
      w4.x = ereg[0].x; w4.y = ereg[1].x; w4.z = ereg[2].x; w4.w = ereg[3].x;
      *reinterpret_cast<float4*>(&es[(cq * 4 + 0) * 68 + k0]) = w4;
      w4.x = ereg[0].y; w4.y = ereg[1].y; w4.z = ereg[2].y; w4.w = ereg[3].y;
      *reinterpret_cast<float4*>(&es[(cq * 4 + 1) * 68 + k0]) = w4;
      w4.x = ereg[0].z; w4.y = ereg[1].z; w4.z = ereg[2].z; w4.w = ereg[3].z;
      *reinterpret_cast<float4*>(&es[(cq * 4 + 2) * 68 + k0]) = w4;
      w4.x = ereg[0].w; w4.y = ereg[1].w; w4.z = ereg[2].w; w4.w = ereg[3].w;
      *reinterpret_cast<float4*>(&es[(cq * 4 + 3) * 68 + k0]) = w4;
    }
    if (tid < 64) ws_s[tid] = wreg;
    __syncthreads();
    if (kt + 1 < ntile) {            // prefetch next tile; latency hides under FMAs
      const float4* g2 = reinterpret_cast<const float4*>(emb + (size_t)(kbase + (kt + 1) * 64) * 64);
      #pragma unroll
      for (int r = 0; r < 4; ++r) ereg[r] = g2[(q * 4 + r) * 16 + cq];
      if (tid < 64) wreg = wsq32[kbase + (kt + 1) * 64 + tid];
    }

    float acc[4][4] = {};
    #pragma unroll 8
    for (int c = 0; c < 64; ++c) {
      float4 zf = *reinterpret_cast<const float4*>(&zs[c * 64 + ty4]);
      float4 ef = *reinterpret_cast<const float4*>(&es[c * 68 + tx4]);
      float z_[4] = {zf.x, zf.y, zf.z, zf.w};
      float e_[4] = {ef.x, ef.y, ef.z, ef.w};
      #pragma unroll
      for (int i = 0; i < 4; ++i)
        #pragma unroll
        for (int j = 0; j < 4; ++j)
          acc[i][j] = __builtin_fmaf(z_[i], e_[j], acc[i][j]);
    }

    #pragma unroll
    for (int i = 0; i < 4; ++i) {
      float zq = zsq_s[ty4 + i];
      #pragma unroll
      for (int j = 0; j < 4; ++j) {
        float t1 = zq + ws_s[tx4 + j];
        float d  = t1 - 2.0f * acc[i][j];
        int ki = kbase + kt * 64 + tx4 + j;
        if (d < bd[i] || (d == bd[i] && ki < bi[i])) { bd[i] = d; bi[i] = ki; }
      }
    }
  }

  // reduce across tx (16 lanes, xor masks 1..8 stay within the tx group)
  #pragma unroll
  for (int i = 0; i < 4; ++i) {
    float d = bd[i]; int ix = bi[i];
    #pragma unroll
    for (int m = 1; m < 16; m <<= 1) {
      float od = __shfl_xor(d, m, 64);
      int   oi = __shfl_xor(ix, m, 64);
      if (od < d || (od == d && oi < ix)) { d = od; ix = oi; }
    }
    if (tx == 0) {
      pd[blockIdx.y * numVec + vi0 + ty4 + i] = d;
      pi[blockIdx.y * numVec + vi0 + ty4 + i] = ix;
    }
  }
}

// ---- fused ksplit-reduce + cubic upsample (or direct gather for pn==16) ----
// grid NELEM/256. Block = fixed (b, c), covers all 256 output pixels.
__global__ __launch_bounds__(256) void k_up(
    const float* __restrict__ pd, const int* __restrict__ pi,
    const float* __restrict__ emb, float* __restrict__ hup,
    int pn, int ksplit) {
  __shared__ float td[256];
  __shared__ int   ti[256];
  __shared__ int   tok_s[256];
  __shared__ float wsh[16][4];
  __shared__ int   i0sh[16];

  int t = threadIdx.x;
  int i = blockIdx.x * 256 + t;
  int p = i & 255; int c = (i >> 8) & 63; int b = i >> 14;
  int P = pn * pn;
  int numVec = BB * P;
  int R = 256 / P;          // split-groups
  int v = t % P, sg = t / P;

  float bd = FLT_MAX; int bi = 0x7fffffff;
  for (int s = sg; s < ksplit; s += R) {
    float cd = pd[s * numVec + b * P + v]; int ci = pi[s * numVec + b * P + v];
    if (cd < bd || (cd == bd && ci < bi)) { bd = cd; bi = ci; }
  }
  td[t] = bd; ti[t] = bi;
  __syncthreads();
  for (int r = R >> 1; r >= 1; r >>= 1) {
    if (sg < r) {
      float cd = td[t + r * P]; int ci = ti[t + r * P];
      if (cd < td[t] || (cd == td[t] && ci < ti[t])) { td[t] = cd; ti[t] = ci; }
    }
    __syncthreads();
  }
  if (t < P) tok_s[t] = ti[t];
  if (pn < 16 && t < 16) {
    // cubic (Keys a=-0.5) weights, f64, bit-identical to jax's (normalized window)
    double s = (t + 0.5) * ((double)pn / 16.0) - 0.5;
    int i0 = (int)floor(s) - 1;
    int hi = pn - 4; if (hi < 0) hi = 0;
    if (i0 < 0) i0 = 0; if (i0 > hi) i0 = hi;
    double wv[4]; double sum = 0.0;
    #pragma unroll
    for (int qq = 0; qq < 4; ++qq) {
      int ii = i0 + qq;
      double w = 0.0;
      if (ii < pn) {
        double xx = fabs(s - (double)ii);
        if (xx < 1.0)       w = ((1.5 * xx - 2.5) * xx) * xx + 1.0;
        else if (xx < 2.0)  w = ((-0.5 * xx + 2.5) * xx - 4.0) * xx + 2.0;
      }
      wv[qq] = w; sum += w;
    }
    i0sh[t] = i0;
    #pragma unroll
    for (int qq = 0; qq < 4; ++qq) wsh[t][qq] = (float)(wv[qq] / sum);
  }
  __syncthreads();

  if (pn == 16) { hup[i] = emb[(size_t)tok_s[p] * 64 + c]; return; }

  int y = p >> 4, x = p & 15;
  int iy0 = i0sh[y], ix0 = i0sh[x];
  float acc = 0.f;
  #pragma unroll
  for (int ty = 0; ty < 4; ++ty) {
    float wy = wsh[y][ty];
    int iy = iy0 + ty; if (iy > pn - 1) iy = pn - 1;  // zero-weight taps: clamp keeps reads in-bounds
    float tmp = 0.f;
    #pragma unroll
    for (int tx = 0; tx < 4; ++tx) {
      float wx = wsh[x][tx];
      int ix = ix0 + tx; if (ix > pn - 1) ix = pn - 1;
      tmp += wx * emb[(size_t)tok_s[iy * pn + ix] * 64 + c];
    }
    acc += wy * tmp;
  }
  hup[i] = acc;
}

// ---- conv v3: grid (B, 8) -> (image, 8 oc). 256 thr = 4 waves.
// wave w: oc-group (w>>1)*4 (wave-uniform -> LDS weight reads broadcast),
//         pixel half (w&1): each thread a 2x1 pixel pair.
// ins: 16-ic chunks in zero-padded 18x18 LDS tile (no boundary branches),
//      chunk prefetched to regs. Weights: all 8oc x 64ic x 9 staged once,
//      padded to 12 floats -> 2x b128 + 1x b32 per (oc,ic).
// Accumulation chain per (oc,pixel) identical to proven kernel:
//   acc = bias; for ic asc: for tap asc: acc = fma(tap, w, acc).
__global__ __launch_bounds__(256) void k_conv(
    const float* __restrict__ hup, const float* __restrict__ w,
    const float* __restrict__ bias, float* __restrict__ out, float* __restrict__ zr) {
  __shared__ __align__(16) float ins[16][18 * 18];
  __shared__ __align__(16) float wsh[8 * 64 * 12];
  int tid = threadIdx.x;
  int b = blockIdx.x;
  int ocb = blockIdx.y;              // oc base = ocb*8

  // zero the ins tile once (borders persist as 0 across chunks)
  for (int idx = tid; idx < 16 * 324; idx += 256)
    (&ins[0][0])[idx] = 0.f;
  // stage all weights, 9 -> 12 padded
  for (int idx = tid; idx < 8 * 64 * 9; idx += 256) {
    int ocic = idx / 9, t = idx - ocic * 9;
    wsh[ocic * 12 + t] = w[(size_t)ocb * 8 * 64 * 9 + idx];
  }

  const int wid = tid >> 6, lane = tid & 63;
  const int ocg = wid >> 1;          // 0/1 -> 4 oc each
  const int ph = (wid & 1) * 64 + lane;  // patch id in [0,128)
  const int x = ph & 15, y2 = ph >> 4;   // pixels (2*y2, x), (2*y2+1, x)

  float acc[4][2];
  #pragma unroll
  for (int j = 0; j < 4; ++j) {
    float bv = bias[ocb * 8 + ocg * 4 + j];
    acc[j][0] = bv; acc[j][1] = bv;
  }

  const float* hb = hup + (size_t)b * 64 * NPIX;
  float sreg[16];
  #pragma unroll
  for (int r = 0; r < 16; ++r) sreg[r] = hb[r * 256 + tid];   // chunk 0 (ic 0-15)

  for (int cc = 0; cc < 4; ++cc) {
    __syncthreads();                 // ins free for overwrite
    #pragma unroll
    for (int r = 0; r < 16; ++r) {
      int idx = r * 256 + tid;
      int icl = idx >> 8, p = idx & 255;
      ins[icl][((p >> 4) + 1) * 18 + (p & 15) + 1] = sreg[r];
    }
    __syncthreads();
    if (cc < 3) {
      #pragma unroll
      for (int r = 0; r < 16; ++r) sreg[r] = hb[(cc + 1) * 4096 + r * 256 + tid];
    }

    #pragma unroll 2
    for (int icl = 0; icl < 16; ++icl) {
      // 4x3 tap block serving both pixels
      float vt[4][3];
      const float* ip = &ins[icl][y2 * 2 * 18 + x];
      #pragma unroll
      for (int r = 0; r < 4; ++r)
        #pragma unroll
        for (int cxx = 0; cxx < 3; ++cxx)
          vt[r][cxx] = ip[r * 18 + cxx];

      int ic = cc * 16 + icl;
      #pragma unroll
      for (int j = 0; j < 4; ++j) {
        const float* wp = &wsh[((ocg * 4 + j) * 64 + ic) * 12];
        float4 wa = *reinterpret_cast<const float4*>(wp);
        float4 wb = *reinterpret_cast<const float4*>(wp + 4);
        float w8 = wp[8];
        float wv[9] = {wa.x, wa.y, wa.z, wa.w, wb.x, wb.y, wb.z, wb.w, w8};
        float a0 = acc[j][0], a1 = acc[j][1];
        #pragma unroll
        for (int dy = 0; dy < 3; ++dy)
          #pragma unroll
          for (int dx = 0; dx < 3; ++dx) {
            float wt = wv[dy * 3 + dx];
            a0 = __builtin_fmaf(vt[dy][dx], wt, a0);
            a1 = __builtin_fmaf(vt[dy + 1][dx], wt, a1);
          }
        acc[j][0] = a0; acc[j][1] = a1;
      }
    }
  }

  #pragma unroll
  for (int j = 0; j < 4; ++j) {
    int oc = ocb * 8 + ocg * 4 + j;
    #pragma unroll
    for (int r = 0; r < 2; ++r) {
      size_t gi = ((size_t)b * 64 + oc) * NPIX + (y2 * 2 + r) * 16 + x;
      float h = hup[gi];
      float ho = 0.5f * h + 0.5f * acc[j][r];
      out[gi] += ho;
      zr[gi]  -= ho;
    }
  }
}

extern "C" void kernel_launch(void* const* d_in, const int* in_sizes, int n_in,
                              void* d_out, int out_size, void* d_ws, size_t ws_size,
                              hipStream_t stream) {
  const float* f    = (const float*)d_in[0];
  const float* emb  = (const float*)d_in[1];
  const float* phiw = (const float*)d_in[2];
  const float* phib = (const float*)d_in[3];
  float* out = (float*)d_out;

  float* ws  = (float*)d_ws;
  float* zr    = ws;                       // 524288
  float* zd    = ws + 524288;              // 524288
  float* hup   = ws + 1048576;             // 524288
  float* wsq32 = ws + 1572864;             // 8192
  float* pd    = ws + 1581056;             // 65536 (max ksplit*numVec)
  int*   pi    = (int*)(ws + 1646592);     // 65536

  // --- PHI_IDX: replicate numpy linspace + argmin in doubles ---
  double start = 1.0 / 3.0 / 4.0;
  double stop  = 1.0 - 1.0 / 3.0 / 4.0;
  double step  = (stop - start) / 3.0;
  double ticks[4] = { start, 1.0 * step + start, 2.0 * step + start, stop };
  int phi_idx[5];
  for (int si = 0; si < 5; ++si) {
    double xx = si / 4.0;
    int bj = 0; double bdd = fabs(ticks[0] - xx);
    for (int j = 1; j < 4; ++j) { double dd = fabs(ticks[j] - xx); if (dd < bdd) { bdd = dd; bj = j; } }
    phi_idx[si] = bj;
  }

  static const int MSarr[5] = {1, 2, 4, 8, 16};

  k_prep<<<NELEM / 256, 256, 0, stream>>>(f, zr, out, emb, wsq32);

  const int KS[5] = {128, 32, 16, 32, 8};
  for (int si = 0; si < 5; ++si) {
    int pn = MSarr[si], pnpn = pn * pn, numVec = BB * pnpn;
    const float* zsrc;
    if (si < 4) {
      int n = BB * CC * pnpn;
      k_down<<<(n + 255) / 256, 256, 0, stream>>>(zr, zd, pn);
      zsrc = zd;
    } else {
      zsrc = zr;
    }
    int ksplit = KS[si], kchunk = KK / ksplit;
    if (si >= 3) {
      dim3 g(numVec / 64, ksplit);
      k_argmin_mm<<<g, 256, 0, stream>>>(zsrc, emb, wsq32, pd, pi, numVec, pnpn, kchunk);
    } else {
      dim3 g((numVec + 31) / 32, ksplit);
      k_argmin<<<g, 256, 0, stream>>>(zsrc, emb, wsq32, pd, pi, numVec, pnpn, kchunk);
    }
    k_up<<<NELEM / 256, 256, 0, stream>>>(pd, pi, emb, hup, pn, ksplit);
    int pidx = phi_idx[si];
    k_conv<<<dim3(BB, 8), 256, 0, stream>>>(hup, phiw + pidx * 64 * 64 * 9,
                                            phib + pidx * 64, out, zr);
  }
}